// Round 7
// baseline (321.378 us; speedup 1.0000x reference)
//
#include <hip/hip_runtime.h>
#include <hip/hip_bf16.h>

#define NSAMP   480000
#define NFRAMES 3000
#define NFFT    400
#define NFREQ   201
#define NMELS   80
#define HOP     160
#define BATCH   64
#define TT      64
#define TBLK    47                                // ceil(3000/64)
#define SPANU   10496                             // (TT-1)*HOP + 416 bf16 samples
#define NFRAG   26
#define KSTEPS  13
#define MKSTEPS 7
#define PWS     232                               // pw row stride (ushorts)
#define BCHUNK  512                               // ushorts per (nf,ks) chunk
#define BTILE   (NFRAG * BCHUNK)                  // 13312 ush = 26 KB per K-step tile
#define LDS_B0  SPANU
#define LDS_PW  SPANU                             // pw aliases B buffers after K-loop
#define LDS_TOT (SPANU + 3 * BTILE)               // 50432 ush = 100,864 B -> 1 block/CU
#define FEAT_ELEMS (BATCH * NMELS * NFRAMES)
#define OUT_ELEMS  (FEAT_ELEMS + BATCH * NFRAMES)
#define TWO_PI  6.283185307179586f
#define WFRAG_ELEMS (NFRAG * KSTEPS * 64 * 8)     // 173056
#define MFRAG_ELEMS (5 * MKSTEPS * 64 * 8)        // 17920
#define WFRAG_BYTES (WFRAG_ELEMS * 2)
#define MFRAG_BYTES (MFRAG_ELEMS * 2)

typedef __attribute__((ext_vector_type(8))) short bf16x8;
typedef __attribute__((ext_vector_type(4))) float f32x4;

static __device__ __forceinline__ ushort f2bf(float x) {
    __hip_bfloat16 h = __float2bfloat16(x);
    return *reinterpret_cast<ushort*>(&h);
}

// async global->LDS, 16B per lane; LDS dest is wave-uniform base + lane*16 (HW).
static __device__ __forceinline__ void gld16(const ushort* g, ushort* l) {
    __builtin_amdgcn_global_load_lds(
        (const __attribute__((address_space(1))) unsigned int*)g,
        (__attribute__((address_space(3))) unsigned int*)l, 16, 0, 0);
}

// wfrag: B-frags of DFT W[k][n]; n=nf*16+(l&15) (even n: cos f=n/2, odd: -sin), k=ks*32+8*(l>>4)+j.
// mfrag: A-frags of MF^T: mel=Mf*16+(l&15), k=freq=ks*32+8*(l>>4)+j.
__global__ __launch_bounds__(256)
void fill_tables_k(ushort* __restrict__ wf, ushort* __restrict__ mfr,
                   const float* __restrict__ mf, unsigned* __restrict__ wmax) {
    const int t = blockIdx.x * 256 + threadIdx.x;
    if (t < WFRAG_ELEMS / 8) {
        const int lane = t & 63;
        const int fk = t >> 6;
        const int ks = fk % KSTEPS;
        const int nf = fk / KSTEPS;
        const int n = nf * 16 + (lane & 15);
        const int kbase = ks * 32 + 8 * (lane >> 4);
        #pragma unroll
        for (int j = 0; j < 8; ++j) {
            const int k = kbase + j;
            float val = 0.f;
            if (n < 2 * NFREQ && k < NFFT) {
                const int f = n >> 1;
                const float win = 0.5f - 0.5f * cosf(TWO_PI * (float)k / (float)NFFT);
                const int r = (f * k) % NFFT;
                const float ph = (float)r * (TWO_PI / (float)NFFT);
                float sv, cv;
                sincosf(ph, &sv, &cv);
                val = (n & 1) ? (-sv * win) : (cv * win);
            }
            wf[(size_t)t * 8 + j] = f2bf(val);
        }
    } else if (t < WFRAG_ELEMS / 8 + MFRAG_ELEMS / 8) {
        const int u = t - WFRAG_ELEMS / 8;
        const int lane = u & 63;
        const int fk = u >> 6;
        const int ks = fk % MKSTEPS;
        const int Mf = fk / MKSTEPS;
        const int mel = Mf * 16 + (lane & 15);
        const int kbase = ks * 32 + 8 * (lane >> 4);
        #pragma unroll
        for (int j = 0; j < 8; ++j) {
            const int freq = kbase + j;
            const float val = (freq < NFREQ) ? mf[freq * NMELS + mel] : 0.f;
            mfr[(size_t)u * 8 + j] = f2bf(val);
        }
    }
    if (blockIdx.x == 0 && threadIdx.x < BATCH) wmax[threadIdx.x] = 0u;
}

// Stage K-step ks into buffer ldsB. Waves 0,1 own 4 chunks; waves 2-7 own 3.
static __device__ __forceinline__ void stageB(const ushort* __restrict__ wfrag,
                                              ushort* ldsB, int ks, int wv, int l) {
    #pragma unroll
    for (int j = 0; j < 4; ++j) {
        const int c = wv + 8 * j;                  // wave-uniform chunk id
        if (c < NFRAG)
            gld16(wfrag + ((size_t)(c * KSTEPS + ks) << 9) + (l << 3),
                  ldsB + c * BCHUNK);
    }
}

__global__ __launch_bounds__(512, 2)
void stft_mel_mfma_k(const float* __restrict__ wav, const ushort* __restrict__ wfrag,
                     const ushort* __restrict__ mfrag,
                     float* __restrict__ out, unsigned* __restrict__ wmax) {
    __shared__ __align__(16) ushort lds[LDS_TOT];

    const int b   = blockIdx.y;
    const int t0  = blockIdx.x * TT;
    const int tid = threadIdx.x;
    const int l   = tid & 63;
    const int wv  = tid >> 6;                      // 0..7
    const int mw  = wv >> 2;                       // M-half (frames 0-31 / 32-63)
    const int nw  = wv & 3;                        // N-set: nf = nw + 4i

    // Prologue: stage buffers 0 and 1; latency hides under span staging.
    stageB(wfrag, lds + LDS_B0, 0, wv, l);
    stageB(wfrag, lds + LDS_B0 + BTILE, 1, wv, l);

    // Stage overlapped span as bf16. Fast path (no reflect) for interior blocks.
    const float* w = wav + (size_t)b * NSAMP;
    const int g0 = t0 * HOP - (NFFT / 2);
    if (g0 >= 0 && g0 + SPANU <= NSAMP) {
        for (int i = tid * 4; i < SPANU; i += 2048) {
            const float4 v = *reinterpret_cast<const float4*>(w + g0 + i);
            ushort4 u;
            u.x = f2bf(v.x); u.y = f2bf(v.y); u.z = f2bf(v.z); u.w = f2bf(v.w);
            *reinterpret_cast<ushort4*>(&lds[i]) = u;
        }
    } else {
        for (int i = tid * 4; i < SPANU; i += 2048) {
            ushort4 u;
            #pragma unroll
            for (int j = 0; j < 4; ++j) {
                int idx = g0 + i + j;
                idx = (idx < 0) ? -idx : idx;
                idx = (idx >= NSAMP) ? (2 * NSAMP - 2 - idx) : idx;
                ((ushort*)&u)[j] = f2bf(w[idx]);
            }
            *reinterpret_cast<ushort4*>(&lds[i]) = u;
        }
    }
    __syncthreads();   // full drain: span ds_writes + stage(0),stage(1) landed

    f32x4 acc[7][2];
    #pragma unroll
    for (int i = 0; i < 7; ++i)
        #pragma unroll
        for (int m = 0; m < 2; ++m)
            acc[i][m] = (f32x4){0.f, 0.f, 0.f, 0.f};

    const ushort* aRow = lds + (mw * 32 + (l & 15)) * HOP + 8 * (l >> 4);

    // 3-deep pipeline: stage(c+2) in flight across intervals; never vmcnt(0) mid-loop.
    #pragma unroll
    for (int c = 0; c < KSTEPS; ++c) {
        if (c <= KSTEPS - 3)
            stageB(wfrag, lds + LDS_B0 + ((c + 2) % 3) * BTILE, c + 2, wv, l);

        const ushort* bbase = lds + LDS_B0 + (c % 3) * BTILE + (l << 3);
        const bf16x8 a0 = *reinterpret_cast<const bf16x8*>(aRow + c * 32);
        const bf16x8 a1 = *reinterpret_cast<const bf16x8*>(aRow + 16 * HOP + c * 32);
        #pragma unroll
        for (int i = 0; i < 7; ++i) {
            const int nf = nw + 4 * i;
            if (nf < NFRAG) {
                const bf16x8 bf = *reinterpret_cast<const bf16x8*>(bbase + nf * BCHUNK);
                acc[i][0] = __builtin_amdgcn_mfma_f32_16x16x32_bf16(a0, bf, acc[i][0], 0, 0, 0);
                acc[i][1] = __builtin_amdgcn_mfma_f32_16x16x32_bf16(a1, bf, acc[i][1], 0, 0, 0);
            }
        }

        if (c <= KSTEPS - 3) {
            // own stage(c+2) loads may stay in flight; stage(c+1) must have landed.
            if (wv < 2) asm volatile("s_waitcnt vmcnt(4)" ::: "memory");
            else        asm volatile("s_waitcnt vmcnt(3)" ::: "memory");
            __builtin_amdgcn_sched_barrier(0);
            __builtin_amdgcn_s_barrier();
            __builtin_amdgcn_sched_barrier(0);
        } else if (c == KSTEPS - 2) {
            asm volatile("s_waitcnt vmcnt(0)" ::: "memory");
            __builtin_amdgcn_sched_barrier(0);
            __builtin_amdgcn_s_barrier();
            __builtin_amdgcn_sched_barrier(0);
        } else {
            __syncthreads();           // end of K-loop: all reads of buf done
        }
    }

    // pw[frame][freq] (bf16, stride PWS) aliases B buffers; all B-reads complete.
    // Zero mel-K padding cols (201..223).
    for (int i = tid; i < TT * 23; i += 512) {
        const int r = i / 23;
        const int cc = 201 + i - r * 23;
        lds[LDS_PW + r * PWS + cc] = 0;
    }
    // power = re^2+im^2 (adjacent lanes), scatter as bf16.
    #pragma unroll
    for (int i = 0; i < 7; ++i) {
        const int nf = nw + 4 * i;
        if (nf < NFRAG) {
            #pragma unroll
            for (int m = 0; m < 2; ++m) {
                const f32x4 v = acc[i][m];
                #pragma unroll
                for (int r = 0; r < 4; ++r) {
                    float p = v[r] * v[r];
                    p += __shfl_xor(p, 1);
                    if (!(l & 1)) {
                        const int f = 8 * nf + ((l & 15) >> 1);
                        const int fr = mw * 32 + 16 * m + 4 * (l >> 4) + r;
                        if (f < NFREQ) lds[LDS_PW + fr * PWS + f] = f2bf(p);
                    }
                }
            }
        }
    }
    __syncthreads();

    // Mel GEMM: 20 tiles (Mf 0..4 x ff 0..3); wave wv takes tiles wv, wv+8, wv+16.
    float lmax = -3.0e38f;
    #pragma unroll
    for (int q = 0; q < 3; ++q) {
        const int tile = wv + 8 * q;
        if (tile < 20) {
            const int Mf = tile >> 2;
            const int ff = tile & 3;
            f32x4 mc = (f32x4){0.f, 0.f, 0.f, 0.f};
            #pragma unroll
            for (int ks = 0; ks < MKSTEPS; ++ks) {
                const bf16x8 aT = *reinterpret_cast<const bf16x8*>(
                    mfrag + ((size_t)(Mf * MKSTEPS + ks) * 64 + l) * 8);
                const bf16x8 bP = *reinterpret_cast<const bf16x8*>(
                    lds + LDS_PW + (ff * 16 + (l & 15)) * PWS + 8 * (l >> 4) + 32 * ks);
                mc = __builtin_amdgcn_mfma_f32_16x16x32_bf16(aT, bP, mc, 0, 0, 0);
            }
            #pragma unroll
            for (int r = 0; r < 4; ++r) {
                const int mel = Mf * 16 + 4 * (l >> 4) + r;
                const int frame = t0 + ff * 16 + (l & 15);
                if (frame < NFRAMES) {
                    const float v = log10f(fmaxf(mc[r], 1e-10f));
                    out[((size_t)b * NMELS + mel) * NFRAMES + frame] = v;
                    lmax = fmaxf(lmax, v);
                }
            }
        }
    }

    #pragma unroll
    for (int off = 32; off > 0; off >>= 1)
        lmax = fmaxf(lmax, __shfl_xor(lmax, off));
    if (l == 0) {
        const unsigned bits = __float_as_uint(lmax);
        const unsigned key = bits ^ ((bits & 0x80000000u) ? 0xFFFFFFFFu : 0x80000000u);
        atomicMax(&wmax[b], key);
    }
}

__global__ __launch_bounds__(256)
void finalize_k(float* __restrict__ out, const unsigned* __restrict__ wmax,
                const int* __restrict__ valid) {
    const int i = blockIdx.x * 256 + threadIdx.x;
    if (i < FEAT_ELEMS) {
        const int b = i / (NMELS * NFRAMES);
        const unsigned key = wmax[b];
        const unsigned bits = key ^ ((key & 0x80000000u) ? 0x80000000u : 0xFFFFFFFFu);
        const float mx = __uint_as_float(bits);
        float v = out[i];
        v = fmaxf(v, mx - 8.0f);
        out[i] = (v + 4.0f) * 0.25f;
    } else if (i < OUT_ELEMS) {
        const int j = i - FEAT_ELEMS;
        const int bb = j / NFRAMES;
        const int tf = j - bb * NFRAMES;
        out[i] = (tf * HOP < valid[bb]) ? 1.0f : 0.0f;
    }
}

extern "C" void kernel_launch(void* const* d_in, const int* in_sizes, int n_in,
                              void* d_out, int out_size, void* d_ws, size_t ws_size,
                              hipStream_t stream) {
    const float* wav   = (const float*)d_in[0];
    const int*   valid = (const int*)d_in[1];
    const float* mf    = (const float*)d_in[2];
    float* out = (float*)d_out;

    ushort*   wfrag = (ushort*)d_ws;
    ushort*   mfrag = (ushort*)((char*)d_ws + WFRAG_BYTES);
    unsigned* wmax  = (unsigned*)((char*)d_ws + WFRAG_BYTES + MFRAG_BYTES);

    const int fill_items = WFRAG_ELEMS / 8 + MFRAG_ELEMS / 8;
    fill_tables_k<<<(fill_items + 255) / 256, 256, 0, stream>>>(wfrag, mfrag, mf, wmax);
    dim3 g(TBLK, BATCH);
    stft_mel_mfma_k<<<g, 512, 0, stream>>>(wav, wfrag, mfrag, out, wmax);
    finalize_k<<<(OUT_ELEMS + 255) / 256, 256, 0, stream>>>(out, wmax, valid);
}

// Round 8
// 270.526 us; speedup vs baseline: 1.1880x; 1.1880x over previous
//
#include <hip/hip_runtime.h>
#include <hip/hip_bf16.h>

#define NSAMP   480000
#define NFRAMES 3000
#define NFFT    400
#define NFREQ   201
#define NMELS   80
#define HOP     160
#define BATCH   64
#define TT      64
#define TBLK    47                                // ceil(3000/64)
#define SPANU   10496                             // (TT-1)*HOP + 416 bf16 samples
#define NFRAG32 13                                // N-frags of 32 (402 -> 416)
#define KS32    25                                // K-steps of 16 (400 exact)
#define MKSTEPS 7
#define PWS     232                               // pw row stride (ushorts)
#define PWTOT   (TT * PWS)                        // 14848 ush = 29.7 KB (span aliases low 21 KB)
#define FEAT_ELEMS (BATCH * NMELS * NFRAMES)
#define OUT_ELEMS  (FEAT_ELEMS + BATCH * NFRAMES)
#define TWO_PI  6.283185307179586f
#define WF32_ELEMS (NFRAG32 * KS32 * 64 * 8)      // 166400
#define MFRAG_ELEMS (5 * MKSTEPS * 64 * 8)        // 17920
#define WF32_BYTES (WF32_ELEMS * 2)
#define MFRAG_BYTES (MFRAG_ELEMS * 2)

typedef __attribute__((ext_vector_type(8))) short bf16x8;
typedef __attribute__((ext_vector_type(4))) float f32x4;
typedef __attribute__((ext_vector_type(16))) float f32x16;

static __device__ __forceinline__ ushort f2bf(float x) {
    __hip_bfloat16 h = __float2bfloat16(x);
    return *reinterpret_cast<ushort*>(&h);
}

// wf32: B-frags of DFT W[k][n] for 32x32x16: n=nf*32+(l&31) (even n: cos f=n/2, odd: -sin),
//       k = ks*16 + 8*(l>>5) + j.
// mfrag: A-frags of MF^T (16x16x32): mel=Mf*16+(l&15), k=freq=ks*32+8*(l>>4)+j.
__global__ __launch_bounds__(256)
void fill_tables_k(ushort* __restrict__ wf, ushort* __restrict__ mfr,
                   const float* __restrict__ mf, unsigned* __restrict__ wmax) {
    const int t = blockIdx.x * 256 + threadIdx.x;
    if (t < WF32_ELEMS / 8) {
        const int lane = t & 63;
        const int fk = t >> 6;
        const int ks = fk % KS32;
        const int nf = fk / KS32;
        const int n = nf * 32 + (lane & 31);
        const int kbase = ks * 16 + 8 * (lane >> 5);
        #pragma unroll
        for (int j = 0; j < 8; ++j) {
            const int k = kbase + j;
            float val = 0.f;
            if (n < 2 * NFREQ && k < NFFT) {
                const int f = n >> 1;
                const float win = 0.5f - 0.5f * cosf(TWO_PI * (float)k / (float)NFFT);
                const int r = (f * k) % NFFT;              // exact angle reduction
                const float ph = (float)r * (TWO_PI / (float)NFFT);
                float sv, cv;
                sincosf(ph, &sv, &cv);
                val = (n & 1) ? (-sv * win) : (cv * win);
            }
            wf[(size_t)t * 8 + j] = f2bf(val);
        }
    } else if (t < WF32_ELEMS / 8 + MFRAG_ELEMS / 8) {
        const int u = t - WF32_ELEMS / 8;
        const int lane = u & 63;
        const int fk = u >> 6;
        const int ks = fk % MKSTEPS;
        const int Mf = fk / MKSTEPS;
        const int mel = Mf * 16 + (lane & 15);
        const int kbase = ks * 32 + 8 * (lane >> 4);
        #pragma unroll
        for (int j = 0; j < 8; ++j) {
            const int freq = kbase + j;
            const float val = (freq < NFREQ) ? mf[freq * NMELS + mel] : 0.f;
            mfr[(size_t)u * 8 + j] = f2bf(val);
        }
    }
    if (blockIdx.x == 0 && threadIdx.x < BATCH) wmax[threadIdx.x] = 0u;
}

__global__ __launch_bounds__(512, 4)   // force VGPR<=128 -> 2 blocks/CU
void stft_mel_mfma_k(const float* __restrict__ wav, const ushort* __restrict__ wfrag,
                     const ushort* __restrict__ mfrag,
                     float* __restrict__ out, unsigned* __restrict__ wmax) {
    __shared__ __align__(16) ushort lds[PWTOT];   // [0,SPANU) = span during K-loop; pw after

    const int b   = blockIdx.y;
    const int t0  = blockIdx.x * TT;
    const int tid = threadIdx.x;
    const int l   = tid & 63;
    const int wv  = tid >> 6;                      // 0..7
    const int mw  = wv >> 2;                       // M-half: frames mw*32..+31
    const int nw  = wv & 3;                        // N-set: nf = nw + 4i (nw0: i<4, else i<3)

    // Stage overlapped span as bf16. Fast path (no reflect) for interior blocks.
    const float* w = wav + (size_t)b * NSAMP;
    const int g0 = t0 * HOP - (NFFT / 2);
    if (g0 >= 0 && g0 + SPANU <= NSAMP) {
        for (int i = tid * 4; i < SPANU; i += 2048) {
            const float4 v = *reinterpret_cast<const float4*>(w + g0 + i);
            ushort4 u;
            u.x = f2bf(v.x); u.y = f2bf(v.y); u.z = f2bf(v.z); u.w = f2bf(v.w);
            *reinterpret_cast<ushort4*>(&lds[i]) = u;
        }
    } else {
        for (int i = tid * 4; i < SPANU; i += 2048) {
            ushort4 u;
            #pragma unroll
            for (int j = 0; j < 4; ++j) {
                int idx = g0 + i + j;
                idx = (idx < 0) ? -idx : idx;
                idx = (idx >= NSAMP) ? (2 * NSAMP - 2 - idx) : idx;
                ((ushort*)&u)[j] = f2bf(w[idx]);
            }
            *reinterpret_cast<ushort4*>(&lds[i]) = u;
        }
    }
    __syncthreads();   // span ready; the ONLY barrier before the epilogue

    // Accumulators: 4 N-frags x 16 f32 (nw!=0 uses 3).
    f32x16 acc[4];
    #pragma unroll
    for (int i = 0; i < 4; ++i)
        #pragma unroll
        for (int j = 0; j < 16; ++j) acc[i][j] = 0.f;

    // A: lane l reads span row (mw*32 + (l&31)), k = 8*(l>>5) + 16*ks  (16B ds_read_b128).
    const ushort* aBase = lds + (mw * 32 + (l & 31)) * HOP + 8 * (l >> 5);
    // B: per (nf,ks) chunk of 512 ush; lane offset l*8.
    const ushort* gB = wfrag + (l << 3);

    bf16x8 aa[2], bb[2][4];
    aa[0] = *reinterpret_cast<const bf16x8*>(aBase);
    #pragma unroll
    for (int i = 0; i < 4; ++i)
        if (i < 3 || nw == 0)
            bb[0][i] = *reinterpret_cast<const bf16x8*>(
                gB + ((size_t)((nw + 4 * i) * KS32) << 9));

    // Barrier-free K-loop: B double-buffered in regs, 1 step ahead.
    #pragma unroll
    for (int ks = 0; ks < KS32; ++ks) {
        const int cur = ks & 1, nxt = cur ^ 1;
        if (ks + 1 < KS32) {
            aa[nxt] = *reinterpret_cast<const bf16x8*>(aBase + 16 * (ks + 1));
            #pragma unroll
            for (int i = 0; i < 4; ++i)
                if (i < 3 || nw == 0)
                    bb[nxt][i] = *reinterpret_cast<const bf16x8*>(
                        gB + ((size_t)((nw + 4 * i) * KS32 + ks + 1) << 9));
        }
        #pragma unroll
        for (int i = 0; i < 4; ++i)
            if (i < 3 || nw == 0)
                acc[i] = __builtin_amdgcn_mfma_f32_32x32x16_bf16(aa[cur], bb[cur][i], acc[i], 0, 0, 0);
    }
    __syncthreads();   // all span reads done; pw may overwrite

    // Zero mel-K padding cols (201..231).
    for (int i = tid; i < TT * 31; i += 512) {
        const int r = i / 31;
        const int cc = 201 + i - r * 31;
        lds[r * PWS + cc] = 0;
    }
    // power = re^2+im^2 (adjacent lanes = adjacent N-cols), scatter pw[frame][freq] bf16.
    // C-layout 32x32: col=l&31, row=(reg&3)+8*(reg>>2)+4*(l>>5).
    #pragma unroll
    for (int i = 0; i < 4; ++i) {
        if (i < 3 || nw == 0) {
            const int nf = nw + 4 * i;
            #pragma unroll
            for (int reg = 0; reg < 16; ++reg) {
                float p = acc[i][reg] * acc[i][reg];
                p += __shfl_xor(p, 1);
                if (!(l & 1)) {
                    const int f = nf * 16 + ((l & 31) >> 1);
                    const int fr = mw * 32 + (reg & 3) + 8 * (reg >> 2) + 4 * (l >> 5);
                    if (f < NFREQ) lds[fr * PWS + f] = f2bf(p);
                }
            }
        }
    }
    __syncthreads();

    // Mel GEMM (16x16x32): 20 tiles (Mf 0..4 x ff 0..3); wave wv takes wv, wv+8, wv+16.
    float lmax = -3.0e38f;
    #pragma unroll
    for (int q = 0; q < 3; ++q) {
        const int tile = wv + 8 * q;
        if (tile < 20) {
            const int Mf = tile >> 2;
            const int ff = tile & 3;
            f32x4 mc = (f32x4){0.f, 0.f, 0.f, 0.f};
            #pragma unroll
            for (int ks = 0; ks < MKSTEPS; ++ks) {
                const bf16x8 aT = *reinterpret_cast<const bf16x8*>(
                    mfrag + ((size_t)(Mf * MKSTEPS + ks) * 64 + l) * 8);
                const bf16x8 bP = *reinterpret_cast<const bf16x8*>(
                    lds + (ff * 16 + (l & 15)) * PWS + 8 * (l >> 4) + 32 * ks);
                mc = __builtin_amdgcn_mfma_f32_16x16x32_bf16(aT, bP, mc, 0, 0, 0);
            }
            #pragma unroll
            for (int r = 0; r < 4; ++r) {
                const int mel = Mf * 16 + 4 * (l >> 4) + r;
                const int frame = t0 + ff * 16 + (l & 15);
                if (frame < NFRAMES) {
                    const float v = log10f(fmaxf(mc[r], 1e-10f));
                    out[((size_t)b * NMELS + mel) * NFRAMES + frame] = v;
                    lmax = fmaxf(lmax, v);
                }
            }
        }
    }

    #pragma unroll
    for (int off = 32; off > 0; off >>= 1)
        lmax = fmaxf(lmax, __shfl_xor(lmax, off));
    if (l == 0) {
        const unsigned bits = __float_as_uint(lmax);
        const unsigned key = bits ^ ((bits & 0x80000000u) ? 0xFFFFFFFFu : 0x80000000u);
        atomicMax(&wmax[b], key);
    }
}

__global__ __launch_bounds__(256)
void finalize_k(float* __restrict__ out, const unsigned* __restrict__ wmax,
                const int* __restrict__ valid) {
    const int i = blockIdx.x * 256 + threadIdx.x;
    if (i < FEAT_ELEMS) {
        const int b = i / (NMELS * NFRAMES);
        const unsigned key = wmax[b];
        const unsigned bits = key ^ ((key & 0x80000000u) ? 0x80000000u : 0xFFFFFFFFu);
        const float mx = __uint_as_float(bits);
        float v = out[i];
        v = fmaxf(v, mx - 8.0f);
        out[i] = (v + 4.0f) * 0.25f;
    } else if (i < OUT_ELEMS) {
        const int j = i - FEAT_ELEMS;
        const int bb = j / NFRAMES;
        const int tf = j - bb * NFRAMES;
        out[i] = (tf * HOP < valid[bb]) ? 1.0f : 0.0f;
    }
}

extern "C" void kernel_launch(void* const* d_in, const int* in_sizes, int n_in,
                              void* d_out, int out_size, void* d_ws, size_t ws_size,
                              hipStream_t stream) {
    const float* wav   = (const float*)d_in[0];
    const int*   valid = (const int*)d_in[1];
    const float* mf    = (const float*)d_in[2];
    float* out = (float*)d_out;

    ushort*   wfrag = (ushort*)d_ws;
    ushort*   mfrag = (ushort*)((char*)d_ws + WF32_BYTES);
    unsigned* wmax  = (unsigned*)((char*)d_ws + WF32_BYTES + MFRAG_BYTES);

    const int fill_items = WF32_ELEMS / 8 + MFRAG_ELEMS / 8;
    fill_tables_k<<<(fill_items + 255) / 256, 256, 0, stream>>>(wfrag, mfrag, mf, wmax);
    dim3 g(TBLK, BATCH);
    stft_mel_mfma_k<<<g, 512, 0, stream>>>(wav, wfrag, mfrag, out, wmax);
    finalize_k<<<(OUT_ELEMS + 255) / 256, 256, 0, stream>>>(out, wmax, valid);
}